// Round 8
// baseline (153.616 us; speedup 1.0000x reference)
//
#include <hip/hip_runtime.h>
#include <math.h>

// Problem constants (match reference)
constexpr int kVerts = 5000;
constexpr int kFaces = 10000;
constexpr int kHalf  = kFaces / 2;
constexpr int kPts   = 16384;   // BATCH * N_PTS = 2 * 8192
constexpr int kOuter = 4;
constexpr int kInner = 50;

#define SCALE 10.0f

// 2-wide fp32 vector: backend lowers <2 x float> arithmetic to v_pk_*_f32
// (one instruction driving BOTH solve chains -> half the issue slots/point).
typedef float v2 __attribute__((ext_vector_type(2)));

// ---------------------------------------------------------------------------
// Compile-time Adam bias-correction table (paired rb1/rb2 per step).
// ---------------------------------------------------------------------------
struct BiasTab { float rb[2 * kInner]; };
constexpr BiasTab make_tab() {
    BiasTab t{};
    float b1 = 1.0f, b2 = 1.0f;
    for (int i = 0; i < kInner; ++i) {
        b1 *= 0.9f; b2 *= 0.999f;
        t.rb[2 * i + 0] = 1.0f / (1.0f - b1);
        t.rb[2 * i + 1] = 1.0f / (1.0f - b2);
    }
    return t;
}
__device__ constexpr BiasTab kTab = make_tab();

// ---------------------------------------------------------------------------
// Kernel 0: precompute triangle centers once (bit-identical *_rn formula).
// ---------------------------------------------------------------------------
__global__ __launch_bounds__(256)
void centers_kernel(const float* __restrict__ mesh_V,
                    const int*   __restrict__ mesh_F,
                    float4*      __restrict__ cent)
{
    const int f = blockIdx.x * 256 + threadIdx.x;
    if (f >= kFaces) return;
    const int i0 = mesh_F[f * 3 + 0];
    const int i1 = mesh_F[f * 3 + 1];
    const int i2 = mesh_F[f * 3 + 2];
    const float cx = __fdiv_rn(__fadd_rn(__fadd_rn(mesh_V[i0*3+0], mesh_V[i1*3+0]), mesh_V[i2*3+0]), 3.0f);
    const float cy = __fdiv_rn(__fadd_rn(__fadd_rn(mesh_V[i0*3+1], mesh_V[i1*3+1]), mesh_V[i2*3+1]), 3.0f);
    const float cz = __fdiv_rn(__fadd_rn(__fadd_rn(mesh_V[i0*3+2], mesh_V[i1*3+2]), mesh_V[i2*3+2]), 3.0f);
    const float cc = __fadd_rn(__fadd_rn(__fmul_rn(cx, cx), __fmul_rn(cy, cy)),
                               __fmul_rn(cz, cz));
    cent[f] = make_float4(cx, cy, cz, cc);
}

// ---------------------------------------------------------------------------
// Kernel 1: KNN (K=1) — REVERTED to the Round-5 kernel (measured 51 us).
// Round-7's 4-points/lane rewrite regressed to ~92 us (inferred from totals;
// the top-5 table provably hides kernels): dropping 8->4 waves/SIMD halved
// latency hiding. This version: 512 blocks x 1024, face-half split,
// wave-uniform scalar-ish loads, frozen bit-exact *_rn distance tree.
// ---------------------------------------------------------------------------
#define KNN_PARTS 16

__global__ __launch_bounds__(1024)
void knn_kernel(const float* __restrict__ verts,
                const float4* __restrict__ cent,
                float*        __restrict__ ws_d2,   // [2][kPts]
                int*          __restrict__ ws_f)    // [2][kPts]
{
    __shared__ float s_best[1024];
    __shared__ int   s_bestf[1024];

    const int tid  = threadIdx.x;
    const int lane = tid & 63;
    const int part = __builtin_amdgcn_readfirstlane(tid >> 6);   // 0..15
    const int pg   = blockIdx.x >> 1;
    const int half = blockIdx.x & 1;
    const int p    = pg * 64 + lane;

    const float qx = verts[p * 3 + 0];
    const float qy = verts[p * 3 + 1];
    const float qz = verts[p * 3 + 2];
    const float q2 = __fadd_rn(__fadd_rn(__fmul_rn(qx, qx), __fmul_rn(qy, qy)),
                               __fmul_rn(qz, qz));

    const int fbeg = half * kHalf + (part * kHalf) / KNN_PARTS;
    const int fend = half * kHalf + ((part + 1) * kHalf) / KNN_PARTS;

    float bd0 = INFINITY, bd1 = INFINITY, bd2 = INFINITY, bd3 = INFINITY;
    int   bf0 = 0x7fffffff, bf1 = 0x7fffffff, bf2 = 0x7fffffff, bf3 = 0x7fffffff;

#define KNN_EVAL(FF, C, BD, BF)                                                       \
    {                                                                                 \
        const float dot = __fadd_rn(__fadd_rn(__fmul_rn(qx, (C).x),                   \
                                              __fmul_rn(qy, (C).y)),                  \
                                    __fmul_rn(qz, (C).z));                            \
        const float d2 = __fsub_rn(__fadd_rn(q2, (C).w), __fmul_rn(2.0f, dot));       \
        if (d2 < (BD)) { (BD) = d2; (BF) = (FF); }                                    \
    }

    int f = fbeg;
#pragma unroll 4
    for (; f + 4 <= fend; f += 4) {
        const float4 c0 = cent[f + 0];   // uniform address -> scalar load
        const float4 c1 = cent[f + 1];
        const float4 c2 = cent[f + 2];
        const float4 c3 = cent[f + 3];
        KNN_EVAL(f + 0, c0, bd0, bf0);
        KNN_EVAL(f + 1, c1, bd1, bf1);
        KNN_EVAL(f + 2, c2, bd2, bf2);
        KNN_EVAL(f + 3, c3, bd3, bf3);
    }
    for (; f < fend; ++f) {
        const float4 c0 = cent[f];
        KNN_EVAL(f, c0, bd0, bf0);
    }
#undef KNN_EVAL

    if (bd1 < bd0 || (bd1 == bd0 && bf1 < bf0)) { bd0 = bd1; bf0 = bf1; }
    if (bd3 < bd2 || (bd3 == bd2 && bf3 < bf2)) { bd2 = bd3; bf2 = bf3; }
    if (bd2 < bd0 || (bd2 == bd0 && bf2 < bf0)) { bd0 = bd2; bf0 = bf2; }

    s_best[tid]  = bd0;
    s_bestf[tid] = bf0;
    __syncthreads();
    if (part == 0) {
        float best  = bd0;
        int   bestf = bf0;
        for (int k = 1; k < KNN_PARTS; ++k) {
            const float ob = s_best[tid + 64 * k];
            const int   of = s_bestf[tid + 64 * k];
            if (ob < best || (ob == best && of < bestf)) { best = ob; bestf = of; }
        }
        ws_d2[half * kPts + p] = best;
        ws_f [half * kPts + p] = bestf;
    }
}

// ---------------------------------------------------------------------------
// Kernel 2: solve — Round-7 v2-packed kernel (measured 54.3 us, VGPR 64,
// no scratch), with the candidate merge adapted back to 2 face-halves
// (half 0 wins ties == first occurrence). Math unchanged.
// 128 blocks x 64 threads; thread t handles p = t and p = t + 8192.
// ---------------------------------------------------------------------------
__global__ __launch_bounds__(64, 1)
void solve_kernel(const float* __restrict__ verts,
                  const float* __restrict__ mesh_V,
                  const float* __restrict__ mesh_N,
                  const int*   __restrict__ mesh_F,
                  const float* __restrict__ ws_d2,
                  const int*   __restrict__ ws_f,
                  float*       __restrict__ out)
{
    const int t = blockIdx.x * 64 + threadIdx.x;   // 0..8191
    int fsel[2];

#pragma unroll
    for (int k = 0; k < 2; ++k) {
        const int p = t + k * 8192;
        // merge halves: half 0 wins ties (lower indices) == first occurrence
        const float da = ws_d2[p];
        const float db = ws_d2[kPts + p];
        const int   fa = ws_f[p];
        const int   fb = ws_f[kPts + p];
        fsel[k] = (db < da) ? fb : fa;
        out[p] = (float)fsel[k];
    }

#define LD2(arr, idx0, idx1) (v2){ arr[idx0], arr[idx1] }
    const int fA = fsel[0], fB = fsel[1];
    const int a0 = mesh_F[fA*3+0], a1 = mesh_F[fA*3+1], a2 = mesh_F[fA*3+2];
    const int b0 = mesh_F[fB*3+0], b1 = mesh_F[fB*3+1], b2 = mesh_F[fB*3+2];

    const v2 qx = LD2(verts, t*3+0, (t+8192)*3+0);
    const v2 qy = LD2(verts, t*3+1, (t+8192)*3+1);
    const v2 qz = LD2(verts, t*3+2, (t+8192)*3+2);

    const v2 V0x = LD2(mesh_V, a0*3+0, b0*3+0), V0y = LD2(mesh_V, a0*3+1, b0*3+1), V0z = LD2(mesh_V, a0*3+2, b0*3+2);
    const v2 V1x = LD2(mesh_V, a1*3+0, b1*3+0), V1y = LD2(mesh_V, a1*3+1, b1*3+1), V1z = LD2(mesh_V, a1*3+2, b1*3+2);
    const v2 V2x = LD2(mesh_V, a2*3+0, b2*3+0), V2y = LD2(mesh_V, a2*3+1, b2*3+1), V2z = LD2(mesh_V, a2*3+2, b2*3+2);
    const v2 N0x = LD2(mesh_N, a0*3+0, b0*3+0), N0y = LD2(mesh_N, a0*3+1, b0*3+1), N0z = LD2(mesh_N, a0*3+2, b0*3+2);
    const v2 N1x = LD2(mesh_N, a1*3+0, b1*3+0), N1y = LD2(mesh_N, a1*3+1, b1*3+1), N1z = LD2(mesh_N, a1*3+2, b1*3+2);
    const v2 N2x = LD2(mesh_N, a2*3+0, b2*3+0), N2y = LD2(mesh_N, a2*3+1, b2*3+1), N2z = LD2(mesh_N, a2*3+2, b2*3+2);
#undef LD2

    const v2 E0x = V0x - V2x, E0y = V0y - V2y, E0z = V0z - V2z;
    const v2 E1x = V1x - V2x, E1y = V1y - V2y, E1z = V1z - V2z;
    const v2 F0x = N0x - N2x, F0y = N0y - N2y, F0z = N0z - N2z;
    const v2 F1x = N1x - N2x, F1y = N1y - N2y, F1z = N1z - N2z;

    const v2 txv = qx * SCALE, tyv = qy * SCALE, tzv = qz * SCALE;
    const float GS = 2.0f / (3.0f * 16384.0f);
    const float B1 = 0.9f,  ONE_M_B1 = 1.0f - 0.9f;
    const float B2 = 0.999f, ONE_M_B2 = 1.0f - 0.999f;

    v2 vwu = (v2)(1.0f / 3.0f), vwv = (v2)(1.0f / 3.0f);

    for (int outer = 0; outer < kOuter; ++outer) {
        const v2 bw0 = (1.0f - vwu) - vwv;
        const v2 px = ((vwu * V0x + vwv * V1x) + bw0 * V2x);
        const v2 py = ((vwu * V0y + vwv * V1y) + bw0 * V2y);
        const v2 pz = ((vwu * V0z + vwv * V1z) + bw0 * V2z);
        const v2 dx = px - qx, dy = py - qy, dz = pz - qz;
        const v2 dn = (dx * dx + dy * dy) + dz * dz;
        v2 dd;
        dd.x = __builtin_amdgcn_sqrtf(dn.x);
        dd.y = __builtin_amdgcn_sqrtf(dn.y);

        v2 du = (v2)0.0f, dv = (v2)0.0f;
        v2 mAu = (v2)0.0f, mAv = (v2)0.0f, mAd = (v2)0.0f;
        v2 vAu = (v2)0.0f, vAv = (v2)0.0f, vAd = (v2)0.0f;

#pragma unroll 2
        for (int it = 0; it < kInner; ++it) {
            const float rb1 = kTab.rb[2 * it + 0];   // uniform s_load, both chains
            const float rb2 = kTab.rb[2 * it + 1];

            const v2 bu = vwu + du;
            const v2 bv = vwv + dv;
            const v2 bw = (1.0f - bu) - bv;

            const v2 cVx = ((bu * V0x + bv * V1x) + bw * V2x) * SCALE;
            const v2 cVy = ((bu * V0y + bv * V1y) + bw * V2y) * SCALE;
            const v2 cVz = ((bu * V0z + bv * V1z) + bw * V2z) * SCALE;

            const v2 nrx = (bu * N0x + bv * N1x) + bw * N2x;
            const v2 nry = (bu * N0y + bv * N1y) + bw * N2y;
            const v2 nrz = (bu * N0z + bv * N1z) + bw * N2z;
            const v2 nn  = (nrx * nrx + nry * nry) + nrz * nrz;
            v2 inv;
            inv.x = __builtin_amdgcn_rsqf(nn.x);
            inv.y = __builtin_amdgcn_rsqf(nn.y);
            const v2 nhx = nrx * inv, nhy = nry * inv, nhz = nrz * inv;
            const v2 cNx = nhx * SCALE, cNy = nhy * SCALE, cNz = nhz * SCALE;

            const v2 rx = (cVx + cNx * dd) - txv;
            const v2 ry = (cVy + cNy * dd) - tyv;
            const v2 rz = (cVz + cNz * dd) - tzv;

            const v2 rv0  = (rx * E0x + ry * E0y) + rz * E0z;
            const v2 rv1  = (rx * E1x + ry * E1y) + rz * E1z;
            const v2 rn0  = (rx * F0x + ry * F0y) + rz * F0z;
            const v2 rn1  = (rx * F1x + ry * F1y) + rz * F1z;
            const v2 nf0  = (nhx * F0x + nhy * F0y) + nhz * F0z;
            const v2 nf1  = (nhx * F1x + nhy * F1y) + nhz * F1z;
            const v2 nr_r = (nhx * rx + nhy * ry) + nhz * rz;

            const v2 gu = GS * (SCALE * rv0 + (dd * SCALE) * ((rn0 - nr_r * nf0) * inv));
            const v2 gv = GS * (SCALE * rv1 + (dd * SCALE) * ((rn1 - nr_r * nf1) * inv));
            const v2 gd = GS * (SCALE * nr_r);

            mAu = B1 * mAu + ONE_M_B1 * gu;
            mAv = B1 * mAv + ONE_M_B1 * gv;
            mAd = B1 * mAd + ONE_M_B1 * gd;
            vAu = B2 * vAu + ONE_M_B2 * (gu * gu);
            vAv = B2 * vAv + ONE_M_B2 * (gv * gv);
            vAd = B2 * vAd + ONE_M_B2 * (gd * gd);

            const v2 au = vAu * rb2 + 1e-16f;
            const v2 av = vAv * rb2 + 1e-16f;
            const v2 ad = vAd * rb2 + 1e-16f;
            v2 su, sv, sd;
            su.x = __builtin_amdgcn_rsqf(au.x);  su.y = __builtin_amdgcn_rsqf(au.y);
            sv.x = __builtin_amdgcn_rsqf(av.x);  sv.y = __builtin_amdgcn_rsqf(av.y);
            sd.x = __builtin_amdgcn_rsqf(ad.x);  sd.y = __builtin_amdgcn_rsqf(ad.y);
            du -= 0.01f * (mAu * rb1) * su;
            dv -= 0.01f * (mAv * rb1) * sv;
            dd -= 0.01f * (mAd * rb1) * sd;
        }
        vwu += du;
        vwv += dv;
    }

#pragma unroll
    for (int k = 0; k < 2; ++k) {
        const int p = t + k * 8192;
        const float u = (k == 0) ? vwu.x : vwu.y;
        const float v = (k == 0) ? vwv.x : vwv.y;
        out[kPts + 2 * p + 0] = u;
        out[kPts + 2 * p + 1] = v;
        out[3 * kPts + p]     = 0.0f;   // outlier_mask = False
    }
}

extern "C" void kernel_launch(void* const* d_in, const int* in_sizes, int n_in,
                              void* d_out, int out_size, void* d_ws, size_t ws_size,
                              hipStream_t stream) {
    const float* verts  = (const float*)d_in[0];
    const float* mesh_V = (const float*)d_in[1];
    const float* mesh_N = (const float*)d_in[2];
    const int*   mesh_F = (const int*)d_in[3];
    float* out = (float*)d_out;

    // workspace: centers | d2 candidates [2][kPts] | face candidates [2][kPts]
    float4* ws_cent = (float4*)d_ws;                                    // 160 KB
    float*  ws_d2   = (float*)((char*)d_ws + kFaces * sizeof(float4));  // 128 KB
    int*    ws_f    = (int*)((char*)ws_d2 + 2 * kPts * sizeof(float));  // 128 KB

    hipLaunchKernelGGL(centers_kernel, dim3((kFaces + 255) / 256), dim3(256), 0, stream,
                       mesh_V, mesh_F, ws_cent);
    hipLaunchKernelGGL(knn_kernel,     dim3(2 * kPts / 64), dim3(1024), 0, stream,
                       verts, ws_cent, ws_d2, ws_f);
    hipLaunchKernelGGL(solve_kernel,   dim3(8192 / 64), dim3(64), 0, stream,
                       verts, mesh_V, mesh_N, mesh_F, ws_d2, ws_f, out);
}